// Round 18
// baseline (1360.937 us; speedup 1.0000x reference)
//
#include <hip/hip_runtime.h>
#include <hip/hip_bf16.h>
#include <stdint.h>

// Problem constants (fixed by reference)
#define BATCH 16
#define NPTS  8192
#define NCH   6
#define NGRP  512   // NUM_GROUPS (FPS samples)
#define GSZ   32    // GROUP_SIZE (kNN)

#define TPB    1024            // threads per block (both roles)
#define FPS_PPT 8              // fps: contiguous mapping, idx = tid*8 + j
#define FPS_W   16
#define GPB     4              // knn groups per block-iteration (4 x 256 thr)
#define NTICK   (BATCH + BATCH * NGRP / GPB)  // 16 + 2048 tickets
#define NKNN    64             // persistent knn worker blocks

typedef float v2f __attribute__((ext_vector_type(2)));

// DPP ctrl encodings (gfx9+): row_shr:N = 0x110|N, row_bcast15/31 = 0x142/0x143
template <int CTRL>
__device__ __forceinline__ float dpp_max_f32(float v) {
  // bound_ctrl=1 -> invalid source lanes read 0; reduced values are squared
  // distances >= 0, so max-with-0 is identity-safe. (validated r7-r17)
  const int t =
      __builtin_amdgcn_update_dpp(0, __float_as_int(v), CTRL, 0xf, 0xf, true);
  return fmaxf(v, __int_as_float(t));
}

template <int CTRL>
__device__ __forceinline__ unsigned dpp_min_u32(unsigned v) {
  // bound_ctrl=0 + old=0xFFFFFFFF -> invalid lanes yield the min identity.
  // (validated r10-r17)
  const int t = __builtin_amdgcn_update_dpp((int)0xFFFFFFFF, (int)v, CTRL,
                                            0xf, 0xf, false);
  const unsigned tu = (unsigned)t;
  return v < tu ? v : tu;
}

// ws layout (uints): [0] ticket counter; [32 + b*32] progress[b]
//
// ---------------------------------------------------------------------------
// ROUND-18: persistent-worker fused kernel. Grid = 16 + 64 blocks (80 CUs,
// 31% of chip) instead of 2064. knn machine work is only ~8500 CU*us (~5% of
// chip-dispatch); 64 persistent workers give 9x consumption headroom over
// the fps production rate (~2 quads/us), while freeing 176 CUs -> the 16
// fps-critical CUs recover boost clock (throttle theory; r17's -30us when
// knn got cheaper is the supporting evidence).
//
// Ticket protocol (r5/r8/r15-r17-validated, deadlock-free): all 80 blocks
// co-resident (1 block/CU via 96.6 KiB LDS); whichever 16 blocks draw
// tickets 0..15 run fps once (they never wait), then join the knn pool.
// knn workers loop tickets until exhausted; quads unlock in ~ticket order.
// fps role: r16 verbatim (r13 LDS tag handshake, publish-before-store).
// knn role: r17 verbatim (tie-fast-path extraction).
// ---------------------------------------------------------------------------
__global__ __launch_bounds__(TPB, 1) void fused_kernel(
    const float* __restrict__ points, float* __restrict__ grouped,
    float* __restrict__ centers, unsigned* __restrict__ ws) {
#pragma clang fp contract(off)
  __shared__ union {
    struct {  // fps role
      float cache[NPTS * 3];                 // xyz cache, 96 KiB
      unsigned long long wdata[2][FPS_W];    // slot data (val,idx)
      unsigned wtag[2][FPS_W];               // slot sequence tags
    } f;
    struct {  // knn role
      unsigned long long wtop[16][GSZ];      // per-wave top-32 candidates
      int knn_sh[GPB][GSZ];
    } k;
  } u;
  __shared__ unsigned ticket_sh;

  const int tid  = threadIdx.x;
  const int lane = tid & 63;
  const int wave = tid >> 6;

  for (;;) {
    if (tid == 0) ticket_sh = atomicAdd(ws, 1u);
    __syncthreads();
    const unsigned ticket = ticket_sh;
    if (ticket >= (unsigned)NTICK) break;

    if (ticket < BATCH) {
      // ========== FPS role: one block per batch (r16 verbatim) ==========
      const int b = (int)ticket;
      const float* P = points + (size_t)b * NPTS * NCH;
      float* C = centers + (size_t)b * NGRP * 3;
      unsigned* prog = ws + 32 + b * 32;

      v2f px[4], py[4], pz[4], md[4];
      {
        float* fx = (float*)px; float* fy = (float*)py; float* fz = (float*)pz;
#pragma unroll
        for (int j = 0; j < FPS_PPT; ++j) {
          const int i = tid * FPS_PPT + j;   // contiguous mapping
          const float x = P[i * 6 + 0];
          const float y = P[i * 6 + 1];
          const float z = P[i * 6 + 2];
          fx[j] = x; fy[j] = y; fz[j] = z;
          u.f.cache[i * 3 + 0] = x;
          u.f.cache[i * 3 + 1] = y;
          u.f.cache[i * 3 + 2] = z;
        }
#pragma unroll
        for (int j = 0; j < 4; ++j)
          md[j] = (v2f){__builtin_inff(), __builtin_inff()};
      }
      if (tid < 32) u.f.wtag[tid >> 4][tid & 15] = 0;  // tags below any k
      __syncthreads();  // cache + tag init ready

      float lx = u.f.cache[0], ly = u.f.cache[1], lz = u.f.cache[2];

      for (int k = 1; k < NGRP; ++k) {
        if (tid == 0) {
          // publish BEFORE the fresh store: release-drain covers only stores
          // >= 1 step old (retired) -> wave 0 never stalls on a fresh store.
          if ((k & 7) == 0)
            __hip_atomic_store(prog, (unsigned)(k - 1), __ATOMIC_RELEASE,
                               __HIP_MEMORY_SCOPE_AGENT);
          C[(k - 1) * 3 + 0] = lx;   // fire-and-forget
          C[(k - 1) * 3 + 1] = ly;
          C[(k - 1) * 3 + 2] = lz;
        }

        // ---- inner: packed min-dist update + per-thread max ----
        const v2f vlx = {lx, lx}, vly = {ly, ly}, vlz = {lz, lz};
        v2f b2 = {-__builtin_inff(), -__builtin_inff()};
#pragma unroll
        for (int j = 0; j < 4; ++j) {
          const v2f dx = px[j] - vlx;
          const v2f dy = py[j] - vly;
          const v2f dz = pz[j] - vlz;
          const v2f d  = (dx * dx + dy * dy) + dz * dz;  // ref order, no fma
          md[j] = __builtin_elementwise_min(md[j], d);
          b2 = __builtin_elementwise_max(b2, md[j]);
        }
        const float bestv = fmaxf(b2.x, b2.y);

        unsigned idxbest = 0;  // min index attaining bestv
#pragma unroll
        for (int j = 3; j >= 0; --j) {
          idxbest = (md[j].y == bestv) ? (unsigned)(tid * 8 + 2 * j + 1) : idxbest;
          idxbest = (md[j].x == bestv) ? (unsigned)(tid * 8 + 2 * j)     : idxbest;
        }

        // ---- level-1: wave max via DPP ----
        float wv = bestv;
        wv = dpp_max_f32<0x111>(wv); wv = dpp_max_f32<0x112>(wv);
        wv = dpp_max_f32<0x114>(wv); wv = dpp_max_f32<0x118>(wv);
        wv = dpp_max_f32<0x142>(wv); wv = dpp_max_f32<0x143>(wv);
        const float wvmax =
            __int_as_float(__builtin_amdgcn_readlane(__float_as_int(wv), 63));
        const int owner = (int)__builtin_ctzll(__ballot(bestv == wvmax));

        const int p = k & 1;
        if (lane == owner) {
          __hip_atomic_store(&u.f.wdata[p][wave],
                             ((unsigned long long)__float_as_uint(wvmax) << 32) |
                                 idxbest,
                             __ATOMIC_RELAXED, __HIP_MEMORY_SCOPE_WORKGROUP);
          __hip_atomic_store(&u.f.wtag[p][wave], (unsigned)k, __ATOMIC_RELEASE,
                             __HIP_MEMORY_SCOPE_WORKGROUP);
        }

        // ---- tag poll replaces __syncthreads (no vmcnt drain) ----
        unsigned tg;
        do {
          tg = __hip_atomic_load(&u.f.wtag[p][lane & 15], __ATOMIC_ACQUIRE,
                                 __HIP_MEMORY_SCOPE_WORKGROUP);
        } while (__ballot(tg == (unsigned)k) != ~0ull);

        // ---- level-2: 16 slots + speculative coord gathers + readlanes ---
        const unsigned long long slot =
            __hip_atomic_load(&u.f.wdata[p][lane & 15], __ATOMIC_RELAXED,
                              __HIP_MEMORY_SCOPE_WORKGROUP);
        const unsigned sidx = (unsigned)(slot & 0xFFFFFFFFull);
        const float    sval = __uint_as_float((unsigned)(slot >> 32));
        const float ccx = u.f.cache[sidx * 3 + 0];
        const float ccy = u.f.cache[sidx * 3 + 1];
        const float ccz = u.f.cache[sidx * 3 + 2];

        float r = sval;
        r = dpp_max_f32<0x111>(r); r = dpp_max_f32<0x112>(r);
        r = dpp_max_f32<0x114>(r); r = dpp_max_f32<0x118>(r);
        const float gmax =
            __int_as_float(__builtin_amdgcn_readlane(__float_as_int(r), 15));
        const int sstar =
            (int)__builtin_ctzll(__ballot(sval == gmax) & 0xFFFFull);
        lx = __int_as_float(__builtin_amdgcn_readlane(__float_as_int(ccx), sstar));
        ly = __int_as_float(__builtin_amdgcn_readlane(__float_as_int(ccy), sstar));
        lz = __int_as_float(__builtin_amdgcn_readlane(__float_as_int(ccz), sstar));
      }
      if (tid == 0) {  // final center + full publish
        C[(NGRP - 1) * 3 + 0] = lx;
        C[(NGRP - 1) * 3 + 1] = ly;
        C[(NGRP - 1) * 3 + 2] = lz;
        __hip_atomic_store(prog, (unsigned)NGRP, __ATOMIC_RELEASE,
                           __HIP_MEMORY_SCOPE_AGENT);
      }
    } else {
      // ====== kNN role: one quad of 4 groups (r17 verbatim) ========
      const unsigned gid = ticket - BATCH;           // g-major ordering
      const int b  = (int)(gid & 15);
      const int g0 = (int)(gid >> 4) * GPB;
      const int sub  = tid >> 8;                     // subunit 0..3
      const int t256 = tid & 255;                    // tid within subunit
      const int g = g0 + sub;
      const float* P = points + (size_t)b * NPTS * NCH;
      const float* cen = centers + ((size_t)b * NGRP + g) * 3;
      unsigned* prog = ws + 32 + b * 32;

      if (tid == 0) {  // spin until all 4 centers are published
        while (__hip_atomic_load(prog, __ATOMIC_ACQUIRE,
                                 __HIP_MEMORY_SCOPE_AGENT) <
               (unsigned)(g0 + GPB))
          __builtin_amdgcn_s_sleep(64);
      }
      __syncthreads();

      // center via agent-scope atomic loads (fresh across XCDs)
      const float cx = __hip_atomic_load(&cen[0], __ATOMIC_RELAXED,
                                         __HIP_MEMORY_SCOPE_AGENT);
      const float cy = __hip_atomic_load(&cen[1], __ATOMIC_RELAXED,
                                         __HIP_MEMORY_SCOPE_AGENT);
      const float cz = __hip_atomic_load(&cen[2], __ATOMIC_RELAXED,
                                         __HIP_MEMORY_SCOPE_AGENT);
      const float cc = (cx * cx + cy * cy) + cz * cz;

      unsigned long long keys[32];
#pragma unroll
      for (int j = 0; j < 32; ++j) {
        const int i = j * 256 + t256;
        const float2 xy = *reinterpret_cast<const float2*>(P + (size_t)i * 6);
        const float x = xy.x, y = xy.y;
        const float z = P[i * 6 + 2];
        const float xx  = (x * x + y * y) + z * z;
        const float dot = fmaf(cz, z, fmaf(cy, y, cx * x));  // einsum fma
        const float d2  = (cc - 2.0f * dot) + xx;
        unsigned uu = __float_as_uint(d2);
        uu = (uu & 0x80000000u) ? ~uu : (uu | 0x80000000u);  // sortable map
        keys[j] = ((unsigned long long)uu << 32) |
                  (unsigned long long)(unsigned)i;
      }

      unsigned long long gm[4];
#pragma unroll
      for (int g2 = 0; g2 < 4; ++g2) {
        unsigned long long m = keys[g2 * 8];
#pragma unroll
        for (int t = 1; t < 8; ++t) {
          const unsigned long long o = keys[g2 * 8 + t];
          m = m < o ? m : o;
        }
        gm[g2] = m;
      }
      unsigned long long lmin;
      {
        const unsigned long long a2 = gm[0] < gm[1] ? gm[0] : gm[1];
        const unsigned long long b3 = gm[2] < gm[3] ? gm[2] : gm[3];
        lmin = a2 < b3 ? a2 : b3;
      }

      // ---- phase 1: per-wave top-32, tie-fast-path rounds ----
      for (int r2 = 0; r2 < GSZ; ++r2) {
        const unsigned vcur = (unsigned)(lmin >> 32);
        const unsigned icur = (unsigned)(lmin & 0xFFFFFFFFull);
        unsigned vm = vcur;
        vm = dpp_min_u32<0x111>(vm); vm = dpp_min_u32<0x112>(vm);
        vm = dpp_min_u32<0x114>(vm); vm = dpp_min_u32<0x118>(vm);
        vm = dpp_min_u32<0x142>(vm); vm = dpp_min_u32<0x143>(vm);
        const unsigned vmin = (unsigned)__builtin_amdgcn_readlane((int)vm, 63);

        const unsigned long long mask = __ballot(vcur == vmin);
        unsigned imin;
        if (__builtin_popcountll(mask) == 1) {  // wave-uniform branch
          imin = (unsigned)__builtin_amdgcn_readlane(
              (int)icur, (int)__builtin_ctzll(mask));
        } else {
          unsigned ic = (vcur == vmin) ? icur : 0xFFFFFFFFu;
          ic = dpp_min_u32<0x111>(ic); ic = dpp_min_u32<0x112>(ic);
          ic = dpp_min_u32<0x114>(ic); ic = dpp_min_u32<0x118>(ic);
          ic = dpp_min_u32<0x142>(ic); ic = dpp_min_u32<0x143>(ic);
          imin = (unsigned)__builtin_amdgcn_readlane((int)ic, 63);
        }
        const unsigned long long wk =
            ((unsigned long long)vmin << 32) | (unsigned long long)imin;

        if (lane == (int)(imin & 63u)) {  // owner removes winner
#pragma unroll
          for (int g2 = 0; g2 < 4; ++g2) {
            if (gm[g2] == wk) {
              unsigned long long m = ~0ull;
#pragma unroll
              for (int t = 0; t < 8; ++t) {
                const int s = g2 * 8 + t;
                if (keys[s] == wk) keys[s] = ~0ull;
                const unsigned long long o = keys[s];
                m = m < o ? m : o;
              }
              gm[g2] = m;
            }
          }
          const unsigned long long a2 = gm[0] < gm[1] ? gm[0] : gm[1];
          const unsigned long long b3 = gm[2] < gm[3] ? gm[2] : gm[3];
          lmin = a2 < b3 ? a2 : b3;
        }
        if (lane == 0) u.k.wtop[wave][r2] = wk;
      }
      __syncthreads();  // wtop ready

      // ---- phase 2: wave 4*sub bitonic-sorts its 128 candidates ----
      if ((wave & 3) == 0) {
        const unsigned long long* flat = &u.k.wtop[4 * sub][0];
        unsigned long long a = flat[lane];
        unsigned long long c = flat[lane + 64];
#pragma unroll
        for (int k2 = 2; k2 <= 128; k2 <<= 1) {
#pragma unroll
          for (int j2 = k2 >> 1; j2 >= 1; j2 >>= 1) {
            if (j2 == 64) {  // within-lane slot exchange (k2 == 128 only)
              const unsigned long long mn = a < c ? a : c;
              const unsigned long long mx = a < c ? c : a;
              a = mn; c = mx;
            } else {
              const bool upa = ((lane & k2) == 0);
              const bool upc = (((lane + 64) & k2) == 0);
              const unsigned long long oa = __shfl_xor(a, j2);
              const unsigned long long oc = __shfl_xor(c, j2);
              const bool low = ((lane & j2) == 0);
              const unsigned long long mna = a < oa ? a : oa;
              const unsigned long long mxa = a < oa ? oa : a;
              const unsigned long long mnc = c < oc ? c : oc;
              const unsigned long long mxc = c < oc ? oc : c;
              a = (low == upa) ? mna : mxa;
              c = (low == upc) ? mnc : mxc;
            }
          }
        }
        if (lane < GSZ)
          u.k.knn_sh[sub][lane] = (int)(unsigned)(a & 0xFFFFFFFFull);
      }
      __syncthreads();

      // gather + center-relative xyz; 192 output floats per group
      float* outg = grouped + ((size_t)b * NGRP + g) * GSZ * NCH;
      if (t256 < GSZ * NCH) {
        const int n = t256 / 6, c2 = t256 % 6;
        const int idx = u.k.knn_sh[sub][n];
        float v = P[idx * 6 + c2];
        if (c2 < 3) {
          const float cv = (c2 == 0) ? cx : (c2 == 1) ? cy : cz;
          v = v - cv;  // exact ref subtract
        }
        outg[t256] = v;
      }
    }
    __syncthreads();  // LDS union quiesced before next ticket
  }
}

extern "C" void kernel_launch(void* const* d_in, const int* in_sizes, int n_in,
                              void* d_out, int out_size, void* d_ws, size_t ws_size,
                              hipStream_t stream) {
  const float* points = (const float*)d_in[0];
  float* out = (float*)d_out;
  float* grouped = out;                                        // [16,512,32,6]
  float* centers = out + (size_t)BATCH * NGRP * GSZ * NCH;     // [16,512,3]
  unsigned* ws = (unsigned*)d_ws;

  // zero ticket counter + progress flags (ws is poisoned 0xAA pre-launch)
  hipMemsetAsync(ws, 0, 4096, stream);
  fused_kernel<<<BATCH + NKNN, TPB, 0, stream>>>(points, grouped, centers, ws);
}

// Round 19
// 689.461 us; speedup vs baseline: 1.9739x; 1.9739x over previous
//
#include <hip/hip_runtime.h>
#include <hip/hip_bf16.h>
#include <stdint.h>

// Problem constants (fixed by reference)
#define BATCH 16
#define NPTS  8192
#define NCH   6
#define NGRP  512   // NUM_GROUPS (FPS samples)
#define GSZ   32    // GROUP_SIZE (kNN)

#define TPB    1024            // threads per block (both roles)
#define FPS_PPT 8              // fps: contiguous mapping, idx = tid*8 + j
#define FPS_W   16
#define GPB     4              // knn groups per block (4 x 256-thread subunits)
#define KNB     (BATCH * NGRP / GPB)  // 2048 knn blocks

typedef float v2f __attribute__((ext_vector_type(2)));

// DPP ctrl encodings (gfx9+): row_shr:N = 0x110|N, row_bcast15/31 = 0x142/0x143
template <int CTRL>
__device__ __forceinline__ float dpp_max_f32(float v) {
  // bound_ctrl=1 -> invalid source lanes read 0; reduced values are squared
  // distances >= 0, so max-with-0 is identity-safe. (validated r7-r17)
  const int t =
      __builtin_amdgcn_update_dpp(0, __float_as_int(v), CTRL, 0xf, 0xf, true);
  return fmaxf(v, __int_as_float(t));
}

template <int CTRL>
__device__ __forceinline__ unsigned dpp_min_u32(unsigned v) {
  // bound_ctrl=0 + old=0xFFFFFFFF -> invalid lanes yield the min identity.
  // (validated r10-r17)
  const int t = __builtin_amdgcn_update_dpp((int)0xFFFFFFFF, (int)v, CTRL,
                                            0xf, 0xf, false);
  const unsigned tu = (unsigned)t;
  return v < tu ? v : tu;
}

// ws layout (uints): [0] ticket counter; [32 + b*32] progress[b]
//
// ---------------------------------------------------------------------------
// ROUND-19 = ROUND-17 VERBATIM (best measured: 697.6 us). One-shot ticket
// blocks (NOT persistent workers: r18's for(;;) loop forced the knn keys[32]
// out of on-chip registers into memory scratch -- 376 MB of spill writes,
// 1360 us). Ticket roles (deadlock-free), 1 block/CU via ~96.6 KiB union LDS
// -> fps CUs never host knn waves.
//
// fps role: r7 structure + r13 LDS tag handshake + publish-before-store.
//   Numerics (bit-exact r2/r4/r7+): d=(dx*dx+dy*dy)+dz*dz, contract off,
//   fminf; argmax-first == value max -> min index (first lane, contiguous
//   mapping, descending-j overwrite); cross-wave min via ballot ctz.
// knn role: r14 two-phase top-32 + r17 tie-fast-path extraction.
//   Numerics (bit-exact r2+): xx left-to-right, dot = fmaf chain (einsum),
//   d2=(cc-2*dot)+xx, sortable-u32 map, u64 keys, ascending-index ties;
//   fast path (unique val-min lane) provably equals the u64 key min.
// Cross-XCD: progress published agent-RELEASE, spun agent-ACQUIRE, centers
// read via agent-scope atomic loads (r5/r8/r15+, absmax 0).
// ---------------------------------------------------------------------------
__global__ __launch_bounds__(TPB, 1) void fused_kernel(
    const float* __restrict__ points, float* __restrict__ grouped,
    float* __restrict__ centers, unsigned* __restrict__ ws) {
#pragma clang fp contract(off)
  __shared__ union {
    struct {  // fps role
      float cache[NPTS * 3];                 // xyz cache, 96 KiB
      unsigned long long wdata[2][FPS_W];    // slot data (val,idx)
      unsigned wtag[2][FPS_W];               // slot sequence tags
    } f;
    struct {  // knn role
      unsigned long long wtop[16][GSZ];      // per-wave top-32 candidates
      int knn_sh[GPB][GSZ];
    } k;
  } u;
  __shared__ unsigned ticket_sh;

  const int tid  = threadIdx.x;
  const int lane = tid & 63;
  const int wave = tid >> 6;

  if (tid == 0) ticket_sh = atomicAdd(ws, 1u);
  __syncthreads();
  const unsigned ticket = ticket_sh;

  if (ticket < BATCH) {
    // ========== FPS role: one block per batch ==========
    const int b = (int)ticket;
    const float* P = points + (size_t)b * NPTS * NCH;
    float* C = centers + (size_t)b * NGRP * 3;
    unsigned* prog = ws + 32 + b * 32;

    v2f px[4], py[4], pz[4], md[4];
    {
      float* fx = (float*)px; float* fy = (float*)py; float* fz = (float*)pz;
#pragma unroll
      for (int j = 0; j < FPS_PPT; ++j) {
        const int i = tid * FPS_PPT + j;   // contiguous mapping
        const float x = P[i * 6 + 0];
        const float y = P[i * 6 + 1];
        const float z = P[i * 6 + 2];
        fx[j] = x; fy[j] = y; fz[j] = z;
        u.f.cache[i * 3 + 0] = x;
        u.f.cache[i * 3 + 1] = y;
        u.f.cache[i * 3 + 2] = z;
      }
#pragma unroll
      for (int j = 0; j < 4; ++j)
        md[j] = (v2f){__builtin_inff(), __builtin_inff()};
    }
    if (tid < 32) u.f.wtag[tid >> 4][tid & 15] = 0;  // tags below any k
    __syncthreads();  // cache + tag init ready (the ONLY barrier)

    float lx = u.f.cache[0], ly = u.f.cache[1], lz = u.f.cache[2];

    for (int k = 1; k < NGRP; ++k) {
      if (tid == 0) {
        // publish BEFORE the fresh store: release-drain covers only stores
        // >= 1 step old (retired) -> wave 0 never stalls on a fresh store.
        if ((k & 7) == 0)
          __hip_atomic_store(prog, (unsigned)(k - 1), __ATOMIC_RELEASE,
                             __HIP_MEMORY_SCOPE_AGENT);
        // fire-and-forget global store (nothing in-loop waits on it)
        C[(k - 1) * 3 + 0] = lx;
        C[(k - 1) * 3 + 1] = ly;
        C[(k - 1) * 3 + 2] = lz;
      }

      // ---- inner: packed min-dist update + per-thread max ----
      const v2f vlx = {lx, lx}, vly = {ly, ly}, vlz = {lz, lz};
      v2f b2 = {-__builtin_inff(), -__builtin_inff()};
#pragma unroll
      for (int j = 0; j < 4; ++j) {
        const v2f dx = px[j] - vlx;
        const v2f dy = py[j] - vly;
        const v2f dz = pz[j] - vlz;
        const v2f d  = (dx * dx + dy * dy) + dz * dz;  // ref op order, no fma
        md[j] = __builtin_elementwise_min(md[j], d);
        b2 = __builtin_elementwise_max(b2, md[j]);
      }
      const float bestv = fmaxf(b2.x, b2.y);

      // first (min) index attaining bestv: descending scan ends at min j
      unsigned idxbest = 0;
#pragma unroll
      for (int j = 3; j >= 0; --j) {
        idxbest = (md[j].y == bestv) ? (unsigned)(tid * 8 + 2 * j + 1) : idxbest;
        idxbest = (md[j].x == bestv) ? (unsigned)(tid * 8 + 2 * j)     : idxbest;
      }

      // ---- level-1: wave max via DPP (VALU only) ----
      float wv = bestv;
      wv = dpp_max_f32<0x111>(wv); wv = dpp_max_f32<0x112>(wv);
      wv = dpp_max_f32<0x114>(wv); wv = dpp_max_f32<0x118>(wv);
      wv = dpp_max_f32<0x142>(wv); wv = dpp_max_f32<0x143>(wv);
      const float wvmax =
          __int_as_float(__builtin_amdgcn_readlane(__float_as_int(wv), 63));
      const int owner = (int)__builtin_ctzll(__ballot(bestv == wvmax));

      const int p = k & 1;
      if (lane == owner) {
        __hip_atomic_store(&u.f.wdata[p][wave],
                           ((unsigned long long)__float_as_uint(wvmax) << 32) |
                               idxbest,
                           __ATOMIC_RELAXED, __HIP_MEMORY_SCOPE_WORKGROUP);
        __hip_atomic_store(&u.f.wtag[p][wave], (unsigned)k, __ATOMIC_RELEASE,
                           __HIP_MEMORY_SCOPE_WORKGROUP);
      }

      // ---- tag poll replaces __syncthreads (no vmcnt drain) ----
      unsigned tg;
      do {
        tg = __hip_atomic_load(&u.f.wtag[p][lane & 15], __ATOMIC_ACQUIRE,
                               __HIP_MEMORY_SCOPE_WORKGROUP);
      } while (__ballot(tg == (unsigned)k) != ~0ull);

      // ---- level-2: 16 slots + speculative coord gathers + readlanes ----
      const unsigned long long slot =
          __hip_atomic_load(&u.f.wdata[p][lane & 15], __ATOMIC_RELAXED,
                            __HIP_MEMORY_SCOPE_WORKGROUP);
      const unsigned sidx = (unsigned)(slot & 0xFFFFFFFFull);
      const float    sval = __uint_as_float((unsigned)(slot >> 32));
      const float ccx = u.f.cache[sidx * 3 + 0];
      const float ccy = u.f.cache[sidx * 3 + 1];
      const float ccz = u.f.cache[sidx * 3 + 2];

      float r = sval;
      r = dpp_max_f32<0x111>(r); r = dpp_max_f32<0x112>(r);
      r = dpp_max_f32<0x114>(r); r = dpp_max_f32<0x118>(r);
      const float gmax =
          __int_as_float(__builtin_amdgcn_readlane(__float_as_int(r), 15));
      const int sstar =
          (int)__builtin_ctzll(__ballot(sval == gmax) & 0xFFFFull);
      lx = __int_as_float(__builtin_amdgcn_readlane(__float_as_int(ccx), sstar));
      ly = __int_as_float(__builtin_amdgcn_readlane(__float_as_int(ccy), sstar));
      lz = __int_as_float(__builtin_amdgcn_readlane(__float_as_int(ccz), sstar));
    }
    if (tid == 0) {  // final center + full publish (release drains all C)
      C[(NGRP - 1) * 3 + 0] = lx;
      C[(NGRP - 1) * 3 + 1] = ly;
      C[(NGRP - 1) * 3 + 2] = lz;
      __hip_atomic_store(prog, (unsigned)NGRP, __ATOMIC_RELEASE,
                         __HIP_MEMORY_SCOPE_AGENT);
    }
  } else {
    // ====== kNN role: 4 groups per block (tie-fast-path) ========
    const unsigned gid = ticket - BATCH;           // g-major ordering
    const int b  = (int)(gid & 15);
    const int g0 = (int)(gid >> 4) * GPB;
    const int sub  = tid >> 8;                     // subunit 0..3
    const int t256 = tid & 255;                    // tid within subunit
    const int g = g0 + sub;
    const float* P = points + (size_t)b * NPTS * NCH;
    const float* cen = centers + ((size_t)b * NGRP + g) * 3;
    unsigned* prog = ws + 32 + b * 32;

    if (tid == 0) {  // spin until all 4 centers are published
      while (__hip_atomic_load(prog, __ATOMIC_ACQUIRE,
                               __HIP_MEMORY_SCOPE_AGENT) <
             (unsigned)(g0 + GPB))
        __builtin_amdgcn_s_sleep(64);
    }
    __syncthreads();

    // center via agent-scope atomic loads (fresh across XCDs)
    const float cx = __hip_atomic_load(&cen[0], __ATOMIC_RELAXED,
                                       __HIP_MEMORY_SCOPE_AGENT);
    const float cy = __hip_atomic_load(&cen[1], __ATOMIC_RELAXED,
                                       __HIP_MEMORY_SCOPE_AGENT);
    const float cz = __hip_atomic_load(&cen[2], __ATOMIC_RELAXED,
                                       __HIP_MEMORY_SCOPE_AGENT);
    const float cc = (cx * cx + cy * cy) + cz * cz;

    unsigned long long keys[32];
#pragma unroll
    for (int j = 0; j < 32; ++j) {
      const int i = j * 256 + t256;
      const float2 xy = *reinterpret_cast<const float2*>(P + (size_t)i * 6);
      const float x = xy.x, y = xy.y;
      const float z = P[i * 6 + 2];
      const float xx  = (x * x + y * y) + z * z;
      const float dot = fmaf(cz, z, fmaf(cy, y, cx * x));  // einsum fma chain
      const float d2  = (cc - 2.0f * dot) + xx;
      unsigned uu = __float_as_uint(d2);
      uu = (uu & 0x80000000u) ? ~uu : (uu | 0x80000000u);  // sortable map
      keys[j] = ((unsigned long long)uu << 32) | (unsigned long long)(unsigned)i;
    }

    // 4 group mins (8 keys each) + overall min
    unsigned long long gm[4];
#pragma unroll
    for (int g2 = 0; g2 < 4; ++g2) {
      unsigned long long m = keys[g2 * 8];
#pragma unroll
      for (int t = 1; t < 8; ++t) {
        const unsigned long long o = keys[g2 * 8 + t];
        m = m < o ? m : o;
      }
      gm[g2] = m;
    }
    unsigned long long lmin;
    {
      const unsigned long long a2 = gm[0] < gm[1] ? gm[0] : gm[1];
      const unsigned long long b3 = gm[2] < gm[3] ? gm[2] : gm[3];
      lmin = a2 < b3 ? a2 : b3;
    }

    // ---- phase 1: per-wave top-32, NO barriers; tie-fast-path rounds ----
    for (int r2 = 0; r2 < GSZ; ++r2) {
      const unsigned vcur = (unsigned)(lmin >> 32);
      const unsigned icur = (unsigned)(lmin & 0xFFFFFFFFull);
      unsigned vm = vcur;
      vm = dpp_min_u32<0x111>(vm); vm = dpp_min_u32<0x112>(vm);
      vm = dpp_min_u32<0x114>(vm); vm = dpp_min_u32<0x118>(vm);
      vm = dpp_min_u32<0x142>(vm); vm = dpp_min_u32<0x143>(vm);
      const unsigned vmin = (unsigned)__builtin_amdgcn_readlane((int)vm, 63);

      // fast path: unique lane holds vmin -> its icur is the exact
      // (val,idx)-lexicographic min index. Fallback (bit-identical cross-
      // lane val tie, rare): full idx DPP chain, identical to r10-r16.
      const unsigned long long mask = __ballot(vcur == vmin);
      unsigned imin;
      if (__builtin_popcountll(mask) == 1) {  // wave-uniform branch
        imin = (unsigned)__builtin_amdgcn_readlane(
            (int)icur, (int)__builtin_ctzll(mask));
      } else {
        unsigned ic = (vcur == vmin) ? icur : 0xFFFFFFFFu;
        ic = dpp_min_u32<0x111>(ic); ic = dpp_min_u32<0x112>(ic);
        ic = dpp_min_u32<0x114>(ic); ic = dpp_min_u32<0x118>(ic);
        ic = dpp_min_u32<0x142>(ic); ic = dpp_min_u32<0x143>(ic);
        imin = (unsigned)__builtin_amdgcn_readlane((int)ic, 63);
      }
      const unsigned long long wk =
          ((unsigned long long)vmin << 32) | (unsigned long long)imin;

      if (lane == (int)(imin & 63u)) {  // owner removes winner
#pragma unroll
        for (int g2 = 0; g2 < 4; ++g2) {
          if (gm[g2] == wk) {
            unsigned long long m = ~0ull;
#pragma unroll
            for (int t = 0; t < 8; ++t) {
              const int s = g2 * 8 + t;
              if (keys[s] == wk) keys[s] = ~0ull;
              const unsigned long long o = keys[s];
              m = m < o ? m : o;
            }
            gm[g2] = m;
          }
        }
        const unsigned long long a2 = gm[0] < gm[1] ? gm[0] : gm[1];
        const unsigned long long b3 = gm[2] < gm[3] ? gm[2] : gm[3];
        lmin = a2 < b3 ? a2 : b3;
      }
      if (lane == 0) u.k.wtop[wave][r2] = wk;
    }
    __syncthreads();  // wtop ready

    // ---- phase 2: wave 4*sub bitonic-sorts its 128 candidates ----
    if ((wave & 3) == 0) {
      const unsigned long long* flat = &u.k.wtop[4 * sub][0];
      unsigned long long a = flat[lane];
      unsigned long long c = flat[lane + 64];
#pragma unroll
      for (int k2 = 2; k2 <= 128; k2 <<= 1) {
#pragma unroll
        for (int j2 = k2 >> 1; j2 >= 1; j2 >>= 1) {
          if (j2 == 64) {  // within-lane slot exchange (only at k2 == 128)
            const unsigned long long mn = a < c ? a : c;
            const unsigned long long mx = a < c ? c : a;
            a = mn; c = mx;
          } else {
            const bool upa = ((lane & k2) == 0);
            const bool upc = (((lane + 64) & k2) == 0);
            const unsigned long long oa = __shfl_xor(a, j2);
            const unsigned long long oc = __shfl_xor(c, j2);
            const bool low = ((lane & j2) == 0);
            const unsigned long long mna = a < oa ? a : oa;
            const unsigned long long mxa = a < oa ? oa : a;
            const unsigned long long mnc = c < oc ? c : oc;
            const unsigned long long mxc = c < oc ? oc : c;
            a = (low == upa) ? mna : mxa;
            c = (low == upc) ? mnc : mxc;
          }
        }
      }
      if (lane < GSZ) u.k.knn_sh[sub][lane] = (int)(unsigned)(a & 0xFFFFFFFFull);
    }
    __syncthreads();

    // gather + center-relative xyz; 192 output floats per group
    float* outg = grouped + ((size_t)b * NGRP + g) * GSZ * NCH;
    if (t256 < GSZ * NCH) {
      const int n = t256 / 6, c2 = t256 % 6;
      const int idx = u.k.knn_sh[sub][n];
      float v = P[idx * 6 + c2];
      if (c2 < 3) {
        const float cv = (c2 == 0) ? cx : (c2 == 1) ? cy : cz;
        v = v - cv;  // exact ref subtract
      }
      outg[t256] = v;
    }
  }
}

extern "C" void kernel_launch(void* const* d_in, const int* in_sizes, int n_in,
                              void* d_out, int out_size, void* d_ws, size_t ws_size,
                              hipStream_t stream) {
  const float* points = (const float*)d_in[0];
  float* out = (float*)d_out;
  float* grouped = out;                                        // [16,512,32,6]
  float* centers = out + (size_t)BATCH * NGRP * GSZ * NCH;     // [16,512,3]
  unsigned* ws = (unsigned*)d_ws;

  // zero ticket counter + progress flags (ws is poisoned 0xAA pre-launch)
  hipMemsetAsync(ws, 0, 4096, stream);
  fused_kernel<<<BATCH + KNB, TPB, 0, stream>>>(points, grouped, centers, ws);
}